// Round 1
// baseline (259.329 us; speedup 1.0000x reference)
//
#include <hip/hip_runtime.h>

// Problem: adjacency_full[i, neighbor_indices[i,k]] = adjacency_values[i,k]
// over a zeroed [N,N] fp32 matrix. N=8192, K=64.
// Write-BW bound: 256 MiB of output writes vs 4 MiB of input reads.

constexpr int N_PATCH = 8192;
constexpr int K_NB = 64;
constexpr int BLOCK = 256;
constexpr int VEC_ITERS = N_PATCH / 4 / BLOCK;  // 8 float4 per thread

__global__ __launch_bounds__(BLOCK)
void scatter_rows_kernel(const float* __restrict__ vals,
                         const int* __restrict__ idx,
                         float* __restrict__ out) {
    __shared__ float row[N_PATCH];  // 32 KiB per block
    const int r = blockIdx.x;
    const int t = threadIdx.x;

    // 1. Zero the row in LDS (float4 = 16B/lane, conflict-free stride pattern)
    float4* rowv = reinterpret_cast<float4*>(row);
    float4 z = make_float4(0.f, 0.f, 0.f, 0.f);
#pragma unroll
    for (int i = 0; i < VEC_ITERS; ++i)
        rowv[t + i * BLOCK] = z;
    __syncthreads();

    // 2. Scatter K=64 values into LDS (first wave only; coalesced global reads)
    if (t < K_NB) {
        const int base = r * K_NB + t;
        const int c = idx[base];
        row[c] = vals[base];
    }
    __syncthreads();

    // 3. Stream the finished row to global, fully coalesced float4 stores
    float4* outv = reinterpret_cast<float4*>(out + (size_t)r * N_PATCH);
#pragma unroll
    for (int i = 0; i < VEC_ITERS; ++i)
        outv[t + i * BLOCK] = rowv[t + i * BLOCK];
}

extern "C" void kernel_launch(void* const* d_in, const int* in_sizes, int n_in,
                              void* d_out, int out_size, void* d_ws, size_t ws_size,
                              hipStream_t stream) {
    const float* vals = (const float*)d_in[0];   // adjacency_values [N,K] fp32
    const int* idx = (const int*)d_in[1];        // neighbor_indices [N,K] int32
    float* out = (float*)d_out;                  // [N,N] fp32

    scatter_rows_kernel<<<N_PATCH, BLOCK, 0, stream>>>(vals, idx, out);
}